// Round 7
// baseline (400.913 us; speedup 1.0000x reference)
//
#include <hip/hip_runtime.h>

// ---------------------------------------------------------------------------
// PASingleRoIExtractor: RoIAlign(out=7, sn=2) on 4 FPN levels + max-combine.
//   1) roi_sort: spatial counting-sort of rois -> perm[] (r5, kept: FETCH
//      165->36MB).
//   2) transpose_flat: NCHW fp32 -> NHWC f16 flat transpose. (unchanged)
//   3) roi_main4b: r5 + two changes:
//      a) KEEP16: empty asm with 16 x "+v" u32x4 operands before each MATH
//         forces all 16 corner loads of a batch simultaneously live ->
//         allocator cannot split batches with mid-batch waits (r5 compiled
//         to 84 VGPR = split batches, ~4-deep effective pipeline).
//      b) fused continuous 8-stage pipeline across both bin passes (no
//         mid-kernel drain); pass-1 entries clamped, store guarded.
//   4) roi_direct fallback if ws too small.
// ---------------------------------------------------------------------------

#define NCH 256
#define NBIN 49
#define WS_F16_BYTES 44564480u

typedef _Float16 half2v __attribute__((ext_vector_type(2)));
typedef unsigned int u32x4 __attribute__((ext_vector_type(4)));

#if defined(__has_builtin)
#if __has_builtin(__builtin_amdgcn_fdot2)
#define HAVE_FDOT2 1
#endif
#if __has_builtin(__builtin_amdgcn_cvt_pkrtz)
#define HAVE_PKRTZ 1
#endif
#endif

__device__ __constant__ int    d_H[4]      = {256, 128, 64, 32};
__device__ __constant__ float  d_scale[4]  = {0.25f, 0.125f, 0.0625f, 0.03125f};
// level base offsets in BYTES into the f16 NHWC workspace
__device__ __constant__ unsigned d_off4b[4] = {0u, 33554432u, 41943040u, 44040192u};
__device__ __constant__ size_t d_offu[4]   = {0, 16777216, 20971520, 22020096}; // f16 units
// flat-transpose tables: P = H*H, blocks of 128 pixels, 4 channel groups
__device__ __constant__ int    d_P[4]      = {65536, 16384, 4096, 1024};
__device__ __constant__ int    d_t2s[4]    = {0, 2048, 2560, 2688};  // block prefix (x4 cg)
__device__ __constant__ int    d_psh[4]    = {9, 7, 5, 3};           // log2(P/128)

__device__ __forceinline__ int pack_h2(float a, float b) {
#ifdef HAVE_PKRTZ
    return __builtin_bit_cast(int, __builtin_amdgcn_cvt_pkrtz(a, b));
#else
    half2v h;
    h.x = (_Float16)a;
    h.y = (_Float16)b;
    return __builtin_bit_cast(int, h);
#endif
}
__device__ __forceinline__ half2v bc_h2(int x) { return __builtin_bit_cast(half2v, x); }
__device__ __forceinline__ half2v bc_h2u(unsigned x) { return __builtin_bit_cast(half2v, x); }

#ifdef HAVE_FDOT2
#define ACC2(uLLc, uLHc, w2, k0)                                                                       \
    acc[k0] = __builtin_amdgcn_fdot2(bc_h2u(__builtin_amdgcn_perm((uLHc), (uLLc), 0x05040100u)), (w2), \
                                     acc[k0], false);                                                  \
    acc[k0 + 1] = __builtin_amdgcn_fdot2(                                                              \
        bc_h2u(__builtin_amdgcn_perm((uLHc), (uLLc), 0x07060302u)), (w2), acc[k0 + 1], false)
#else
#define ACC2(uLLc, uLHc, w2, k0)                                       \
    do {                                                               \
        half2v a_ = bc_h2u(uLLc), b_ = bc_h2u(uLHc);                   \
        float w0_ = (float)(w2).x, w1_ = (float)(w2).y;                \
        acc[k0]     = fmaf((float)a_.x, w0_, acc[k0]);                 \
        acc[k0]     = fmaf((float)b_.x, w1_, acc[k0]);                 \
        acc[k0 + 1] = fmaf((float)a_.y, w0_, acc[k0 + 1]);             \
        acc[k0 + 1] = fmaf((float)b_.y, w1_, acc[k0 + 1]);             \
    } while (0)
#endif

// math for one sample: corners LL,LH,HL,HH in L[0..3], weights from (ye,xe)
__device__ __forceinline__ void math4(float* acc, const u32x4* L, int4 ye, int4 xe) {
    half2v wx = bc_h2(xe.z);
    half2v wlo = bc_h2(ye.z) * wx;  // {wyl*wxl, wyl*wxh}  (v_pk_mul_f16)
    half2v whi = bc_h2(ye.w) * wx;  // {wyh*wxl, wyh*wxh}
    ACC2(L[0].x, L[1].x, wlo, 0);
    ACC2(L[0].y, L[1].y, wlo, 2);
    ACC2(L[0].z, L[1].z, wlo, 4);
    ACC2(L[0].w, L[1].w, wlo, 6);
    ACC2(L[2].x, L[3].x, whi, 0);
    ACC2(L[2].y, L[3].y, whi, 2);
    ACC2(L[2].z, L[3].z, whi, 4);
    ACC2(L[2].w, L[3].w, whi, 6);
}

__device__ __forceinline__ u32x4 ldws(const char* __restrict__ wsb, unsigned off) {
    // uniform base + 32-bit per-lane byte offset -> global_load_dwordx4 saddr form
    return *(const u32x4*)(wsb + off);
}

// 16 corner gathers (4 samples x 4 corners) for one (bin, level) stage
__device__ __forceinline__ void issue16(u32x4* L, const char* __restrict__ wsb, unsigned base,
                                        int4 ye0, int4 ye1, int4 xe0, int4 xe1) {
    L[0]  = ldws(wsb, base + (unsigned)(ye0.x + xe0.x));
    L[1]  = ldws(wsb, base + (unsigned)(ye0.x + xe0.y));
    L[2]  = ldws(wsb, base + (unsigned)(ye0.y + xe0.x));
    L[3]  = ldws(wsb, base + (unsigned)(ye0.y + xe0.y));
    L[4]  = ldws(wsb, base + (unsigned)(ye0.x + xe1.x));
    L[5]  = ldws(wsb, base + (unsigned)(ye0.x + xe1.y));
    L[6]  = ldws(wsb, base + (unsigned)(ye0.y + xe1.x));
    L[7]  = ldws(wsb, base + (unsigned)(ye0.y + xe1.y));
    L[8]  = ldws(wsb, base + (unsigned)(ye1.x + xe0.x));
    L[9]  = ldws(wsb, base + (unsigned)(ye1.x + xe0.y));
    L[10] = ldws(wsb, base + (unsigned)(ye1.y + xe0.x));
    L[11] = ldws(wsb, base + (unsigned)(ye1.y + xe0.y));
    L[12] = ldws(wsb, base + (unsigned)(ye1.x + xe1.x));
    L[13] = ldws(wsb, base + (unsigned)(ye1.x + xe1.y));
    L[14] = ldws(wsb, base + (unsigned)(ye1.y + xe1.x));
    L[15] = ldws(wsb, base + (unsigned)(ye1.y + xe1.y));
}

// math for one full (bin, level) stage: 4 samples, fold into running max
__device__ __forceinline__ void math_stage(float* m, const u32x4* L, int4 ye0, int4 ye1,
                                           int4 xe0, int4 xe1) {
    float acc[8];
#pragma unroll
    for (int k = 0; k < 8; ++k) acc[k] = 0.0f;
    math4(acc, &L[0], ye0, xe0);
    math4(acc, &L[4], ye0, xe1);
    math4(acc, &L[8], ye1, xe0);
    math4(acc, &L[12], ye1, xe1);
#pragma unroll
    for (int k = 0; k < 8; ++k) m[k] = fmaxf(m[k], acc[k] * 0.25f);
}

// ---------------------------------------------------------------------------
// Spatial counting sort of rois: Morton key of center over 16x16 tiles.
// ---------------------------------------------------------------------------
__global__ __launch_bounds__(256) void roi_sort(const float* __restrict__ rois, int nrois,
                                                int* __restrict__ perm) {
    __shared__ unsigned hist[256];
    __shared__ unsigned offs[256];
    const int tid = threadIdx.x;
    hist[tid] = 0;
    __syncthreads();
    for (int i = tid; i < nrois; i += 256) {
        const float* r = rois + (size_t)i * 5;
        float cx = 0.5f * (r[1] + r[3]);
        float cy = 0.5f * (r[2] + r[4]);
        int tx = min(max((int)(cx * (1.0f / 64.0f)), 0), 15);
        int ty = min(max((int)(cy * (1.0f / 64.0f)), 0), 15);
        int k = 0;
#pragma unroll
        for (int bb = 0; bb < 4; ++bb)
            k |= (((tx >> bb) & 1) << (2 * bb)) | (((ty >> bb) & 1) << (2 * bb + 1));
        atomicAdd(&hist[k], 1u);
    }
    __syncthreads();
    if (tid == 0) {
        unsigned acc = 0;
        for (int i = 0; i < 256; ++i) {
            offs[i] = acc;
            acc += hist[i];
        }
    }
    __syncthreads();
    for (int i = tid; i < nrois; i += 256) {
        const float* r = rois + (size_t)i * 5;
        float cx = 0.5f * (r[1] + r[3]);
        float cy = 0.5f * (r[2] + r[4]);
        int tx = min(max((int)(cx * (1.0f / 64.0f)), 0), 15);
        int ty = min(max((int)(cy * (1.0f / 64.0f)), 0), 15);
        int k = 0;
#pragma unroll
        for (int bb = 0; bb < 4; ++bb)
            k |= (((tx >> bb) & 1) << (2 * bb)) | (((ty >> bb) & 1) << (2 * bb + 1));
        unsigned pos = atomicAdd(&offs[k], 1u);
        perm[pos] = i;
    }
}

// ---------------------------------------------------------------------------
// Flat transpose: [C, P] fp32 -> [P, C] f16 per level. 2720 blocks total.
// ---------------------------------------------------------------------------
__global__ __launch_bounds__(256) void transpose_flat(
    const float* __restrict__ f0, const float* __restrict__ f1, const float* __restrict__ f2,
    const float* __restrict__ f3, unsigned short* __restrict__ out) {
    const int b = blockIdx.x;
    const int lvl = (b >= d_t2s[1]) + (b >= d_t2s[2]) + (b >= d_t2s[3]);
    const int rem = b - d_t2s[lvl];
    const int sh = d_psh[lvl];
    const int pb = rem & ((1 << sh) - 1);  // pixel block
    const int cgi = rem >> sh;             // channel group of 64
    const int P = d_P[lvl];
    const float* in = (lvl == 0) ? f0 : (lvl == 1) ? f1 : (lvl == 2) ? f2 : f3;

    const int tid = threadIdx.x;
    const int o8 = tid & 7;   // channel octet within group
    const int g = tid >> 3;   // pixel quad 0..31
    const int p0 = pb * 128 + g * 4;
    const int c0 = cgi * 64 + o8 * 8;

    const float* src = in + (size_t)c0 * P + p0;
    float vv[32];
#pragma unroll
    for (int r = 0; r < 8; ++r)
        *(float4*)&vv[4 * r] = *(const float4*)(src + (size_t)r * P);

    unsigned short* o = out + d_offu[lvl] + (size_t)p0 * NCH + c0;
#pragma unroll
    for (int j = 0; j < 4; ++j) {
        uint4 d;
        d.x = (unsigned)pack_h2(vv[0 * 4 + j], vv[1 * 4 + j]);
        d.y = (unsigned)pack_h2(vv[2 * 4 + j], vv[3 * 4 + j]);
        d.z = (unsigned)pack_h2(vv[4 * 4 + j], vv[5 * 4 + j]);
        d.w = (unsigned)pack_h2(vv[6 * 4 + j], vv[7 * 4 + j]);
        *(uint4*)(o + (size_t)j * NCH) = d;
    }
}

// ---------------------------------------------------------------------------
// Main roi kernel: 4 blocks/roi, 64 ch each. Fused 8-stage pipeline over
// (pass0: lvl0-3, pass1: lvl0-3); KEEP16 forces full 16-load batches live.
// Grid: quarter-major over SORTED rois, bijectively XCD-chunked.
// ---------------------------------------------------------------------------
__global__ __launch_bounds__(256, 2) void roi_main4b(const u32x4* __restrict__ ws,
                                                     const float* __restrict__ rois,
                                                     const int* __restrict__ perm, int nrois,
                                                     float* __restrict__ out) {
    __shared__ float smem[64 * NBIN];  // 12544 B
    __shared__ int4 tbl[4][2][14];     // 1792 B

    const int nwg = (int)gridDim.x;
    const int orig = blockIdx.x;
    const int xcd = orig & 7;
    const int idx = orig >> 3;
    const int q8 = nwg >> 3, r8 = nwg & 7;
    const int wg = (xcd < r8 ? xcd * (q8 + 1) : r8 * (q8 + 1) + (xcd - r8) * q8) + idx;

    const int quarter = wg / nrois;
    const int sidx = wg - quarter * nrois;
    const int n = perm[sidx];

    const int tid = threadIdx.x;
    const float* r = rois + (size_t)n * 5;

    if (tid < 112) {
        int lvl = tid / 28;
        int e = tid % 28;
        int axis = e / 14;  // 0 = y, 1 = x
        int s = e % 14;
        int H = d_H[lvl];
        float sc = d_scale[lvl];
        float a = (axis ? r[1] : r[2]) * sc;
        float b2 = (axis ? r[3] : r[4]) * sc;
        float binsz = fmaxf(b2 - a, 1.0f) * (1.0f / 7.0f);
        float g = (float)(s >> 1) + 0.25f + 0.5f * (float)(s & 1);
        float coord = a + g * binsz;
        float valid = (coord > -1.0f && coord < (float)H) ? 1.0f : 0.0f;
        float c = fminf(fmaxf(coord, 0.0f), (float)H - 1.0f);
        int lo = (int)floorf(c);
        int hi = min(lo + 1, H - 1);
        float whi = (c - (float)lo) * valid;
        float wlo = (1.0f - (c - (float)lo)) * valid;
        int mult = axis ? 512 : H * 512;  // byte offsets
        int4 t;
        t.x = lo * mult;
        t.y = hi * mult;
        if (axis) {
            t.z = pack_h2(wlo, whi);
            t.w = 0;
        } else {
            t.z = pack_h2(wlo, wlo);
            t.w = pack_h2(whi, whi);
        }
        tbl[lvl][axis][s] = t;
    }
    __syncthreads();

    const int p = tid & 7;   // octet within this quarter's 64 channels
    const int h = tid >> 3;  // 0..31
    const int octet = quarter * 8 + p;
    const char* __restrict__ wsb = (const char*)ws;

    unsigned lvlbase[4];
#pragma unroll
    for (int l = 0; l < 4; ++l) lvlbase[l] = d_off4b[l] + (unsigned)octet * 16u;

    const int b0 = h;                    // pass-0 bin, always valid
    const int b1 = h + 32;               // pass-1 bin, valid iff < 49
    const int b1c = min(b1, NBIN - 1);   // clamped for safe table access
    const int iy0 = b0 / 7, ix0 = b0 - (b0 / 7) * 7;
    const int iy1 = b1c / 7, ix1 = b1c - (b1c / 7) * 7;

#define RD_E(E, lvl, BY, BX)             \
    E##y0 = tbl[lvl][0][2 * (BY)];       \
    E##y1 = tbl[lvl][0][2 * (BY) + 1];   \
    E##x0 = tbl[lvl][1][2 * (BX)];       \
    E##x1 = tbl[lvl][1][2 * (BX) + 1]
#define ISSUE(L, E, lvl) issue16(L, wsb, lvlbase[lvl], E##y0, E##y1, E##x0, E##x1)
#define MATH(M, L, E) math_stage(M, L, E##y0, E##y1, E##x0, E##x1)
#define FENCE() __builtin_amdgcn_sched_barrier(0)
#define KEEP16(L)                                                                        \
    asm volatile("" : "+v"(L[0]), "+v"(L[1]), "+v"(L[2]), "+v"(L[3]), "+v"(L[4]),        \
                      "+v"(L[5]), "+v"(L[6]), "+v"(L[7]), "+v"(L[8]), "+v"(L[9]),        \
                      "+v"(L[10]), "+v"(L[11]), "+v"(L[12]), "+v"(L[13]), "+v"(L[14]),   \
                      "+v"(L[15]))

    float m0[8], m1[8];
#pragma unroll
    for (int k = 0; k < 8; ++k) {
        m0[k] = -3.402823e38f;
        m1[k] = -3.402823e38f;
    }

    u32x4 LA[16], LB[16];
    int4 Ay0, Ay1, Ax0, Ax1, By0, By1, Bx0, Bx1;

    // ---- fused 8-stage pipeline: (p0,l0..3),(p1,l0..3), buffers alternate --
    RD_E(A, 0, iy0, ix0);
    ISSUE(LA, A, 0);
    RD_E(B, 1, iy0, ix0);
    ISSUE(LB, B, 1);
    FENCE();
    KEEP16(LA);
    MATH(m0, LA, A);            // s0: p0 lvl0
    FENCE();
    RD_E(A, 2, iy0, ix0);
    ISSUE(LA, A, 2);
    FENCE();
    KEEP16(LB);
    MATH(m0, LB, B);            // s1: p0 lvl1
    FENCE();
    RD_E(B, 3, iy0, ix0);
    ISSUE(LB, B, 3);
    FENCE();
    KEEP16(LA);
    MATH(m0, LA, A);            // s2: p0 lvl2
    FENCE();
    RD_E(A, 0, iy1, ix1);
    ISSUE(LA, A, 0);
    FENCE();
    KEEP16(LB);
    MATH(m0, LB, B);            // s3: p0 lvl3 -> pass 0 done
    FENCE();
#pragma unroll
    for (int k = 0; k < 8; ++k) smem[(p * 8 + k) * NBIN + b0] = m0[k];
    RD_E(B, 1, iy1, ix1);
    ISSUE(LB, B, 1);
    FENCE();
    KEEP16(LA);
    MATH(m1, LA, A);            // s4: p1 lvl0
    FENCE();
    RD_E(A, 2, iy1, ix1);
    ISSUE(LA, A, 2);
    FENCE();
    KEEP16(LB);
    MATH(m1, LB, B);            // s5: p1 lvl1
    FENCE();
    RD_E(B, 3, iy1, ix1);
    ISSUE(LB, B, 3);
    FENCE();
    KEEP16(LA);
    MATH(m1, LA, A);            // s6: p1 lvl2
    FENCE();
    KEEP16(LB);
    MATH(m1, LB, B);            // s7: p1 lvl3
    if (b1 < NBIN) {
#pragma unroll
        for (int k = 0; k < 8; ++k) smem[(p * 8 + k) * NBIN + b1] = m1[k];
    }
#undef RD_E
#undef ISSUE
#undef MATH
#undef FENCE
#undef KEEP16
    __syncthreads();

    float4* o4 = (float4*)(out + (size_t)n * (NCH * NBIN) + (size_t)quarter * (64 * NBIN));
    const float4* s4 = (const float4*)smem;
    for (int i = tid; i < 64 * NBIN / 4; i += 256) o4[i] = s4[i];
}

// ---------------------------------------------------------------------------
// Fallback: direct NCHW fp32 gather (only if ws too small).
// ---------------------------------------------------------------------------
__device__ __forceinline__ int4 make_entry_f(float coord, int size, int mult) {
    float valid = (coord > -1.0f && coord < (float)size) ? 1.0f : 0.0f;
    float c = fminf(fmaxf(coord, 0.0f), (float)size - 1.0f);
    int lo = (int)floorf(c);
    int hi = min(lo + 1, size - 1);
    float whi = (c - (float)lo) * valid;
    float wlo = (1.0f - (c - (float)lo)) * valid;
    int4 r;
    r.x = lo * mult;
    r.y = hi * mult;
    r.z = __float_as_int(wlo);
    r.w = __float_as_int(whi);
    return r;
}

__global__ __launch_bounds__(256) void roi_direct(
    const float* __restrict__ f0, const float* __restrict__ f1, const float* __restrict__ f2,
    const float* __restrict__ f3, const float* __restrict__ rois, float* __restrict__ out) {
    const int n = blockIdx.x;
    const int c = threadIdx.x;
    const float* feats[4] = {f0, f1, f2, f3};
    const float* r = rois + (size_t)n * 5;
    for (int b = 0; b < NBIN; ++b) {
        int by = b / 7;
        int bx = b - by * 7;
        float m = -3.402823e38f;
#pragma unroll
        for (int lvl = 0; lvl < 4; ++lvl) {
            int H = d_H[lvl];
            float sc = d_scale[lvl];
            float x1 = r[1] * sc, y1 = r[2] * sc, x2 = r[3] * sc, y2 = r[4] * sc;
            float bw = fmaxf(x2 - x1, 1.0f) * (1.0f / 7.0f);
            float bh = fmaxf(y2 - y1, 1.0f) * (1.0f / 7.0f);
            const float* f = feats[lvl] + (size_t)c * H * H;
            float acc = 0.0f;
#pragma unroll
            for (int sy = 0; sy < 2; ++sy) {
#pragma unroll
                for (int sx = 0; sx < 2; ++sx) {
                    float yc = y1 + ((float)by + 0.25f + 0.5f * sy) * bh;
                    float xc = x1 + ((float)bx + 0.25f + 0.5f * sx) * bw;
                    int4 ey = make_entry_f(yc, H, H);
                    int4 ex = make_entry_f(xc, H, 1);
                    float wyl = __int_as_float(ey.z), wyh = __int_as_float(ey.w);
                    float wxl = __int_as_float(ex.z), wxh = __int_as_float(ex.w);
                    acc += f[ey.x + ex.x] * wyl * wxl + f[ey.x + ex.y] * wyl * wxh +
                           f[ey.y + ex.x] * wyh * wxl + f[ey.y + ex.y] * wyh * wxh;
                }
            }
            m = fmaxf(m, acc * 0.25f);
        }
        out[((size_t)n * NCH + c) * NBIN + b] = m;
    }
}

extern "C" void kernel_launch(void* const* d_in, const int* in_sizes, int n_in, void* d_out,
                              int out_size, void* d_ws, size_t ws_size, hipStream_t stream) {
    const float* f0 = (const float*)d_in[0];
    const float* f1 = (const float*)d_in[1];
    const float* f2 = (const float*)d_in[2];
    const float* f3 = (const float*)d_in[3];
    const float* rois = (const float*)d_in[4];
    const int nrois = in_sizes[4] / 5;
    float* out = (float*)d_out;

    const size_t need = (size_t)WS_F16_BYTES + (size_t)nrois * 4;
    if (ws_size < need) {
        roi_direct<<<nrois, 256, 0, stream>>>(f0, f1, f2, f3, rois, out);
        return;
    }
    unsigned short* wsp = (unsigned short*)d_ws;
    int* perm = (int*)((char*)d_ws + WS_F16_BYTES);
    roi_sort<<<1, 256, 0, stream>>>(rois, nrois, perm);
    transpose_flat<<<2720, 256, 0, stream>>>(f0, f1, f2, f3, wsp);
    roi_main4b<<<4 * nrois, 256, 0, stream>>>((const u32x4*)d_ws, rois, perm, nrois, out);
}

// Round 8
// 198.676 us; speedup vs baseline: 2.0179x; 2.0179x over previous
//
#include <hip/hip_runtime.h>

// ---------------------------------------------------------------------------
// PASingleRoIExtractor: RoIAlign(out=7, sn=2) on 4 FPN levels + max-combine.
//   1) transpose_flat: NCHW fp32 -> NHWC f16 flat transpose (2720 blocks)
//      + FUSED roi spatial counting sort in extra blocks (disjoint inputs;
//      stream order guarantees completion before roi_main4b). Launches 3->2.
//   2) roi_main4b: EXACT r5 restore - the only clean fast build (84 VGPR,
//      no spill, FETCH 36MB, WRITE 49MB, 73us). r6's KEEP16 spill (VGPR 128,
//      +1.1GB scratch traffic) confirmed the allocator cannot hold 32 live
//      u32x4 tuples; r5's ~2-deep-per-wave pipeline at the measured
//      ~3.5cy/line CU gather service rate is the structural operating point.
//   3) roi_direct fallback if ws too small.
// ---------------------------------------------------------------------------

#define NCH 256
#define NBIN 49
#define WS_F16_BYTES 44564480u
#define T_BLOCKS 2720

typedef _Float16 half2v __attribute__((ext_vector_type(2)));

#if defined(__has_builtin)
#if __has_builtin(__builtin_amdgcn_fdot2)
#define HAVE_FDOT2 1
#endif
#if __has_builtin(__builtin_amdgcn_cvt_pkrtz)
#define HAVE_PKRTZ 1
#endif
#endif

__device__ __constant__ int    d_H[4]      = {256, 128, 64, 32};
__device__ __constant__ float  d_scale[4]  = {0.25f, 0.125f, 0.0625f, 0.03125f};
// level base offsets in BYTES into the f16 NHWC workspace
__device__ __constant__ unsigned d_off4b[4] = {0u, 33554432u, 41943040u, 44040192u};
__device__ __constant__ size_t d_offu[4]   = {0, 16777216, 20971520, 22020096}; // f16 units
// flat-transpose tables: P = H*H, blocks of 128 pixels, 4 channel groups
__device__ __constant__ int    d_P[4]      = {65536, 16384, 4096, 1024};
__device__ __constant__ int    d_t2s[4]    = {0, 2048, 2560, 2688};  // block prefix (x4 cg)
__device__ __constant__ int    d_psh[4]    = {9, 7, 5, 3};           // log2(P/128)

__device__ __forceinline__ int pack_h2(float a, float b) {
#ifdef HAVE_PKRTZ
    return __builtin_bit_cast(int, __builtin_amdgcn_cvt_pkrtz(a, b));
#else
    half2v h;
    h.x = (_Float16)a;
    h.y = (_Float16)b;
    return __builtin_bit_cast(int, h);
#endif
}
__device__ __forceinline__ half2v bc_h2(int x) { return __builtin_bit_cast(half2v, x); }
__device__ __forceinline__ half2v bc_h2u(unsigned x) { return __builtin_bit_cast(half2v, x); }

#ifdef HAVE_FDOT2
#define ACC2(uLLc, uLHc, w2, k0)                                                                       \
    acc[k0] = __builtin_amdgcn_fdot2(bc_h2u(__builtin_amdgcn_perm((uLHc), (uLLc), 0x05040100u)), (w2), \
                                     acc[k0], false);                                                  \
    acc[k0 + 1] = __builtin_amdgcn_fdot2(                                                              \
        bc_h2u(__builtin_amdgcn_perm((uLHc), (uLLc), 0x07060302u)), (w2), acc[k0 + 1], false)
#else
#define ACC2(uLLc, uLHc, w2, k0)                                       \
    do {                                                               \
        half2v a_ = bc_h2u(uLLc), b_ = bc_h2u(uLHc);                   \
        float w0_ = (float)(w2).x, w1_ = (float)(w2).y;                \
        acc[k0]     = fmaf((float)a_.x, w0_, acc[k0]);                 \
        acc[k0]     = fmaf((float)b_.x, w1_, acc[k0]);                 \
        acc[k0 + 1] = fmaf((float)a_.y, w0_, acc[k0 + 1]);             \
        acc[k0 + 1] = fmaf((float)b_.y, w1_, acc[k0 + 1]);             \
    } while (0)
#endif

// math for one sample: corners LL,LH,HL,HH in L[0..3], weights from (ye,xe)
__device__ __forceinline__ void math4(float* acc, const uint4* L, int4 ye, int4 xe) {
    half2v wx = bc_h2(xe.z);
    half2v wlo = bc_h2(ye.z) * wx;  // {wyl*wxl, wyl*wxh}  (v_pk_mul_f16)
    half2v whi = bc_h2(ye.w) * wx;  // {wyh*wxl, wyh*wxh}
    ACC2(L[0].x, L[1].x, wlo, 0);
    ACC2(L[0].y, L[1].y, wlo, 2);
    ACC2(L[0].z, L[1].z, wlo, 4);
    ACC2(L[0].w, L[1].w, wlo, 6);
    ACC2(L[2].x, L[3].x, whi, 0);
    ACC2(L[2].y, L[3].y, whi, 2);
    ACC2(L[2].z, L[3].z, whi, 4);
    ACC2(L[2].w, L[3].w, whi, 6);
}

__device__ __forceinline__ uint4 ldws(const char* __restrict__ wsb, unsigned off) {
    // uniform base + 32-bit per-lane byte offset -> global_load_dwordx4 saddr form
    return *(const uint4*)(wsb + off);
}

// 16 corner gathers (4 samples x 4 corners) for one (bin, level) stage
__device__ __forceinline__ void issue16(uint4* L, const char* __restrict__ wsb, unsigned base,
                                        int4 ye0, int4 ye1, int4 xe0, int4 xe1) {
    L[0]  = ldws(wsb, base + (unsigned)(ye0.x + xe0.x));
    L[1]  = ldws(wsb, base + (unsigned)(ye0.x + xe0.y));
    L[2]  = ldws(wsb, base + (unsigned)(ye0.y + xe0.x));
    L[3]  = ldws(wsb, base + (unsigned)(ye0.y + xe0.y));
    L[4]  = ldws(wsb, base + (unsigned)(ye0.x + xe1.x));
    L[5]  = ldws(wsb, base + (unsigned)(ye0.x + xe1.y));
    L[6]  = ldws(wsb, base + (unsigned)(ye0.y + xe1.x));
    L[7]  = ldws(wsb, base + (unsigned)(ye0.y + xe1.y));
    L[8]  = ldws(wsb, base + (unsigned)(ye1.x + xe0.x));
    L[9]  = ldws(wsb, base + (unsigned)(ye1.x + xe0.y));
    L[10] = ldws(wsb, base + (unsigned)(ye1.y + xe0.x));
    L[11] = ldws(wsb, base + (unsigned)(ye1.y + xe0.y));
    L[12] = ldws(wsb, base + (unsigned)(ye1.x + xe1.x));
    L[13] = ldws(wsb, base + (unsigned)(ye1.x + xe1.y));
    L[14] = ldws(wsb, base + (unsigned)(ye1.y + xe1.x));
    L[15] = ldws(wsb, base + (unsigned)(ye1.y + xe1.y));
}

// math for one full (bin, level) stage: 4 samples, fold into running max
__device__ __forceinline__ void math_stage(float* m, const uint4* L, int4 ye0, int4 ye1,
                                           int4 xe0, int4 xe1) {
    float acc[8];
#pragma unroll
    for (int k = 0; k < 8; ++k) acc[k] = 0.0f;
    math4(acc, &L[0], ye0, xe0);
    math4(acc, &L[4], ye0, xe1);
    math4(acc, &L[8], ye1, xe0);
    math4(acc, &L[12], ye1, xe1);
#pragma unroll
    for (int k = 0; k < 8; ++k) m[k] = fmaxf(m[k], acc[k] * 0.25f);
}

__device__ __forceinline__ int morton_key(const float* __restrict__ r) {
    float cx = 0.5f * (r[1] + r[3]);
    float cy = 0.5f * (r[2] + r[4]);
    int tx = min(max((int)(cx * (1.0f / 64.0f)), 0), 15);
    int ty = min(max((int)(cy * (1.0f / 64.0f)), 0), 15);
    int k = 0;
#pragma unroll
    for (int bb = 0; bb < 4; ++bb)
        k |= (((tx >> bb) & 1) << (2 * bb)) | (((ty >> bb) & 1) << (2 * bb + 1));
    return k;
}

// ---------------------------------------------------------------------------
// Flat transpose [C,P] fp32 -> [P,C] f16 (blocks 0..2719) + fused roi sort
// (block 2720). Sort and transpose touch disjoint data; both complete before
// roi_main4b by stream order.
// ---------------------------------------------------------------------------
__global__ __launch_bounds__(256) void transpose_sort(
    const float* __restrict__ f0, const float* __restrict__ f1, const float* __restrict__ f2,
    const float* __restrict__ f3, unsigned short* __restrict__ out,
    const float* __restrict__ rois, int nrois, int* __restrict__ perm) {
    __shared__ unsigned hist[256];
    __shared__ unsigned offs[256];

    const int b = blockIdx.x;
    const int tid = threadIdx.x;

    if (b >= T_BLOCKS) {
        // ---- spatial counting sort of rois (single block) ----
        hist[tid] = 0;
        __syncthreads();
        for (int i = tid; i < nrois; i += 256)
            atomicAdd(&hist[morton_key(rois + (size_t)i * 5)], 1u);
        __syncthreads();
        if (tid == 0) {
            unsigned acc = 0;
            for (int i = 0; i < 256; ++i) {
                offs[i] = acc;
                acc += hist[i];
            }
        }
        __syncthreads();
        for (int i = tid; i < nrois; i += 256) {
            unsigned pos = atomicAdd(&offs[morton_key(rois + (size_t)i * 5)], 1u);
            perm[pos] = i;
        }
        return;
    }

    const int lvl = (b >= d_t2s[1]) + (b >= d_t2s[2]) + (b >= d_t2s[3]);
    const int rem = b - d_t2s[lvl];
    const int sh = d_psh[lvl];
    const int pb = rem & ((1 << sh) - 1);  // pixel block
    const int cgi = rem >> sh;             // channel group of 64
    const int P = d_P[lvl];
    const float* in = (lvl == 0) ? f0 : (lvl == 1) ? f1 : (lvl == 2) ? f2 : f3;

    const int o8 = tid & 7;   // channel octet within group
    const int g = tid >> 3;   // pixel quad 0..31
    const int p0 = pb * 128 + g * 4;
    const int c0 = cgi * 64 + o8 * 8;

    const float* src = in + (size_t)c0 * P + p0;
    float vv[32];
#pragma unroll
    for (int r = 0; r < 8; ++r)
        *(float4*)&vv[4 * r] = *(const float4*)(src + (size_t)r * P);

    unsigned short* o = out + d_offu[lvl] + (size_t)p0 * NCH + c0;
#pragma unroll
    for (int j = 0; j < 4; ++j) {
        uint4 d;
        d.x = (unsigned)pack_h2(vv[0 * 4 + j], vv[1 * 4 + j]);
        d.y = (unsigned)pack_h2(vv[2 * 4 + j], vv[3 * 4 + j]);
        d.z = (unsigned)pack_h2(vv[4 * 4 + j], vv[5 * 4 + j]);
        d.w = (unsigned)pack_h2(vv[6 * 4 + j], vv[7 * 4 + j]);
        *(uint4*)(o + (size_t)j * NCH) = d;
    }
}

// ---------------------------------------------------------------------------
// Main roi kernel: EXACT r5 build. 4 blocks/roi, 64 ch each, 2 wave-uniform
// bin passes, fenced level-pipelined 16-load batches. Grid: quarter-major
// over SORTED rois, bijectively XCD-chunked.
// ---------------------------------------------------------------------------
__global__ __launch_bounds__(256, 2) void roi_main4b(const uint4* __restrict__ ws,
                                                     const float* __restrict__ rois,
                                                     const int* __restrict__ perm, int nrois,
                                                     float* __restrict__ out) {
    __shared__ float smem[64 * NBIN];  // 12544 B
    __shared__ int4 tbl[4][2][14];     // 1792 B

    const int nwg = (int)gridDim.x;
    const int orig = blockIdx.x;
    const int xcd = orig & 7;
    const int idx = orig >> 3;
    const int q8 = nwg >> 3, r8 = nwg & 7;
    const int wg = (xcd < r8 ? xcd * (q8 + 1) : r8 * (q8 + 1) + (xcd - r8) * q8) + idx;

    const int quarter = wg / nrois;
    const int sidx = wg - quarter * nrois;
    const int n = perm[sidx];

    const int tid = threadIdx.x;
    const float* r = rois + (size_t)n * 5;

    if (tid < 112) {
        int lvl = tid / 28;
        int e = tid % 28;
        int axis = e / 14;  // 0 = y, 1 = x
        int s = e % 14;
        int H = d_H[lvl];
        float sc = d_scale[lvl];
        float a = (axis ? r[1] : r[2]) * sc;
        float b2 = (axis ? r[3] : r[4]) * sc;
        float binsz = fmaxf(b2 - a, 1.0f) * (1.0f / 7.0f);
        float g = (float)(s >> 1) + 0.25f + 0.5f * (float)(s & 1);
        float coord = a + g * binsz;
        float valid = (coord > -1.0f && coord < (float)H) ? 1.0f : 0.0f;
        float c = fminf(fmaxf(coord, 0.0f), (float)H - 1.0f);
        int lo = (int)floorf(c);
        int hi = min(lo + 1, H - 1);
        float whi = (c - (float)lo) * valid;
        float wlo = (1.0f - (c - (float)lo)) * valid;
        // BYTE offsets: pixel = 256ch * 2B = 512 B; y step = H*512 B
        int mult = axis ? 512 : H * 512;
        int4 t;
        t.x = lo * mult;
        t.y = hi * mult;
        if (axis) {
            t.z = pack_h2(wlo, whi);
            t.w = 0;
        } else {
            t.z = pack_h2(wlo, wlo);
            t.w = pack_h2(whi, whi);
        }
        tbl[lvl][axis][s] = t;
    }
    __syncthreads();

    const int p = tid & 7;   // octet within this quarter's 64 channels
    const int h = tid >> 3;  // 0..31
    const int octet = quarter * 8 + p;
    const char* __restrict__ wsb = (const char*)ws;

    unsigned lvlbase[4];
#pragma unroll
    for (int l = 0; l < 4; ++l) lvlbase[l] = d_off4b[l] + (unsigned)octet * 16u;

#define RD_E(E, lvl)                     \
    E##y0 = tbl[lvl][0][2 * by];         \
    E##y1 = tbl[lvl][0][2 * by + 1];     \
    E##x0 = tbl[lvl][1][2 * bx];         \
    E##x1 = tbl[lvl][1][2 * bx + 1]
#define ISSUE(L, E, lvl) issue16(L, wsb, lvlbase[lvl], E##y0, E##y1, E##x0, E##x1)
#define MATH(L, E) math_stage(m, L, E##y0, E##y1, E##x0, E##x1)
#define FENCE() __builtin_amdgcn_sched_barrier(0)

    // two wave-uniform bin passes: b = h, then b = h + 32
#pragma unroll
    for (int pass = 0; pass < 2; ++pass) {
        const int b = h + pass * 32;
        if (b < NBIN) {
            int by = b / 7;
            int bx = b - by * 7;
            float m[8];
#pragma unroll
            for (int k = 0; k < 8; ++k) m[k] = -3.402823e38f;

            // ---- software pipeline over the 4 levels, double-buffered ----
            uint4 LA[16], LB[16];
            int4 Ay0, Ay1, Ax0, Ax1, By0, By1, Bx0, Bx1;

            RD_E(A, 0);
            ISSUE(LA, A, 0);        // lvl0 loads in flight
            RD_E(B, 1);
            ISSUE(LB, B, 1);        // lvl1 loads in flight
            FENCE();
            MATH(LA, A);            // lvl0 math over lvl1 latency
            FENCE();
            RD_E(A, 2);
            ISSUE(LA, A, 2);        // lvl2 loads in flight
            FENCE();
            MATH(LB, B);            // lvl1 math over lvl2 latency
            FENCE();
            RD_E(B, 3);
            ISSUE(LB, B, 3);        // lvl3 loads in flight
            FENCE();
            MATH(LA, A);            // lvl2 math over lvl3 latency
            FENCE();
            MATH(LB, B);            // lvl3 math

#pragma unroll
            for (int k = 0; k < 8; ++k) smem[(p * 8 + k) * NBIN + b] = m[k];
        }
    }
#undef RD_E
#undef ISSUE
#undef MATH
#undef FENCE
    __syncthreads();

    float4* o4 = (float4*)(out + (size_t)n * (NCH * NBIN) + (size_t)quarter * (64 * NBIN));
    const float4* s4 = (const float4*)smem;
    for (int i = tid; i < 64 * NBIN / 4; i += 256) o4[i] = s4[i];
}

// ---------------------------------------------------------------------------
// Fallback: direct NCHW fp32 gather (only if ws too small).
// ---------------------------------------------------------------------------
__device__ __forceinline__ int4 make_entry_f(float coord, int size, int mult) {
    float valid = (coord > -1.0f && coord < (float)size) ? 1.0f : 0.0f;
    float c = fminf(fmaxf(coord, 0.0f), (float)size - 1.0f);
    int lo = (int)floorf(c);
    int hi = min(lo + 1, size - 1);
    float whi = (c - (float)lo) * valid;
    float wlo = (1.0f - (c - (float)lo)) * valid;
    int4 r;
    r.x = lo * mult;
    r.y = hi * mult;
    r.z = __float_as_int(wlo);
    r.w = __float_as_int(whi);
    return r;
}

__global__ __launch_bounds__(256) void roi_direct(
    const float* __restrict__ f0, const float* __restrict__ f1, const float* __restrict__ f2,
    const float* __restrict__ f3, const float* __restrict__ rois, float* __restrict__ out) {
    const int n = blockIdx.x;
    const int c = threadIdx.x;
    const float* feats[4] = {f0, f1, f2, f3};
    const float* r = rois + (size_t)n * 5;
    for (int b = 0; b < NBIN; ++b) {
        int by = b / 7;
        int bx = b - by * 7;
        float m = -3.402823e38f;
#pragma unroll
        for (int lvl = 0; lvl < 4; ++lvl) {
            int H = d_H[lvl];
            float sc = d_scale[lvl];
            float x1 = r[1] * sc, y1 = r[2] * sc, x2 = r[3] * sc, y2 = r[4] * sc;
            float bw = fmaxf(x2 - x1, 1.0f) * (1.0f / 7.0f);
            float bh = fmaxf(y2 - y1, 1.0f) * (1.0f / 7.0f);
            const float* f = feats[lvl] + (size_t)c * H * H;
            float acc = 0.0f;
#pragma unroll
            for (int sy = 0; sy < 2; ++sy) {
#pragma unroll
                for (int sx = 0; sx < 2; ++sx) {
                    float yc = y1 + ((float)by + 0.25f + 0.5f * sy) * bh;
                    float xc = x1 + ((float)bx + 0.25f + 0.5f * sx) * bw;
                    int4 ey = make_entry_f(yc, H, H);
                    int4 ex = make_entry_f(xc, H, 1);
                    float wyl = __int_as_float(ey.z), wyh = __int_as_float(ey.w);
                    float wxl = __int_as_float(ex.z), wxh = __int_as_float(ex.w);
                    acc += f[ey.x + ex.x] * wyl * wxl + f[ey.x + ex.y] * wyl * wxh +
                           f[ey.y + ex.x] * wyh * wxl + f[ey.y + ex.y] * wyh * wxh;
                }
            }
            m = fmaxf(m, acc * 0.25f);
        }
        out[((size_t)n * NCH + c) * NBIN + b] = m;
    }
}

extern "C" void kernel_launch(void* const* d_in, const int* in_sizes, int n_in, void* d_out,
                              int out_size, void* d_ws, size_t ws_size, hipStream_t stream) {
    const float* f0 = (const float*)d_in[0];
    const float* f1 = (const float*)d_in[1];
    const float* f2 = (const float*)d_in[2];
    const float* f3 = (const float*)d_in[3];
    const float* rois = (const float*)d_in[4];
    const int nrois = in_sizes[4] / 5;
    float* out = (float*)d_out;

    const size_t need = (size_t)WS_F16_BYTES + (size_t)nrois * 4;
    if (ws_size < need) {
        roi_direct<<<nrois, 256, 0, stream>>>(f0, f1, f2, f3, rois, out);
        return;
    }
    unsigned short* wsp = (unsigned short*)d_ws;
    int* perm = (int*)((char*)d_ws + WS_F16_BYTES);
    transpose_sort<<<T_BLOCKS + 1, 256, 0, stream>>>(f0, f1, f2, f3, wsp, rois, nrois, perm);
    roi_main4b<<<4 * nrois, 256, 0, stream>>>((const uint4*)d_ws, rois, perm, nrois, out);
}